// Round 9
// baseline (227.435 us; speedup 1.0000x reference)
//
#include <hip/hip_runtime.h>

// GlobalGraphConv: B=4, C=64, N=4096, IC=32
// f[i,j] = a_i + p_j (outer sum); lrelu piecewise-linear =>
// exp(lrelu(a_i+p_j)) factorizes per branch; sort p, softmax row = threshold
// lookup into prefix/suffix chunk sums of weighted g_x rows. O(N^2 C)->O(N C).
// R9: R7's flat grid barrier = 256 serialized RMWs on one line (~26us).
// Hierarchical barrier (16 groups x 16 + root) should be ~4us < 8us dispatch
// gap => fuse rank/sums/output into ONE coop kernel w/ 2 barriers. PreG/SufG
// materialization eliminated: output phase computes chunk offsets in LDS +
// within-chunk remainder with ONE exp/j (w_j = exp(sel*(a_i+q_j))).

#define B  4
#define C  64
#define N  4096
#define IC 32
#define MAGIC 0x13572468
#define NBLK 256

// workspace float offsets
#define OFF_FLAG   248                  // int: C_k nonzero marker
#define OFF_A      256
#define OFF_P      (OFF_A + B*N)        // 16640
#define OFF_Q      (OFF_P + B*N)        // 33024
#define OFF_PERM   (OFF_Q + B*N)        // 49408 (ints)
#define OFF_S1     (OFF_PERM + B*N)     // 65792  B*64*64 chunk channel sums e^q
#define OFF_S2     (OFF_S1 + B*64*64)   // 82176  e^{0.2q}
#define OFF_SC1    (OFF_S2 + B*64*64)   // 98560  B*64 chunk scalar sums e^q
#define OFF_SC2    (OFF_SC1 + B*64)     // 98816  e^{0.2q}
#define OFF_BAR    (OFF_SC2 + B*64)     // 99072  barrier ints (2 slots x 544)
#define OFF_GX     (OFF_BAR + 2048)     // 101120 B*N*64 [b][n][o]

//========== K1: gx = g_w@x + g_b; a,p; C_k zero scan; zero barrier ==========
__global__ __launch_bounds__(256) void k1_gx(
    const float* __restrict__ x, const float* __restrict__ g_w,
    const float* __restrict__ g_b, const float* __restrict__ theta_w,
    const float* __restrict__ theta_b, const float* __restrict__ phi_w,
    const float* __restrict__ phi_b, const float* __restrict__ cp_w,
    const float* __restrict__ Ck, float* __restrict__ ws) {
  __shared__ float gwT[C * C];   // [cc][o]
  __shared__ float xl[C * 16];   // [cc][nn]
  __shared__ float lu[C], lv[C], cst[2];
  const int tid = threadIdx.x;
  const int b = blockIdx.x >> 8;           // 256 blocks per batch
  const int n0 = (blockIdx.x & 255) << 4;  // 16 nodes per block
  if (blockIdx.x == 0) {                   // zero barrier slots for dispatch 2
    for (int j = tid; j < 1088; j += 256) ((int*)ws)[OFF_BAR + j] = 0;
  }
  for (int idx = tid; idx < C * C; idx += 256) {
    int o = idx >> 6, cc = idx & 63;
    gwT[cc * C + o] = g_w[idx];
  }
  for (int idx = tid; idx < C * 16; idx += 256) {
    int cc = idx >> 4, nn = idx & 15;
    xl[idx] = x[(size_t)((b << 6) + cc) * N + n0 + nn];
  }
  if (tid < 64) {
    float u = 0.f;
    for (int k = 0; k < IC; ++k) u += cp_w[k] * theta_w[k * C + tid];
    lu[tid] = u;
  } else if (tid < 128) {
    int c = tid - 64;
    float v = 0.f;
    for (int k = 0; k < IC; ++k) v += cp_w[IC + k] * phi_w[k * C + c];
    lv[c] = v;
  } else if (tid == 128) {
    float ca = 0.f, cp2 = 0.f;
    for (int k = 0; k < IC; ++k) { ca += cp_w[k] * theta_b[k]; cp2 += cp_w[IC + k] * phi_b[k]; }
    cst[0] = ca; cst[1] = cp2;
  }
  __syncthreads();
  if (tid < 16) {   // a,p: one thread per node
    float au = cst[0], pu = cst[1];
    for (int cc = 0; cc < C; ++cc) {
      float xv = xl[cc * 16 + tid];
      au += lu[cc] * xv;
      pu += lv[cc] * xv;
    }
    ws[OFF_A + (b << 12) + n0 + tid] = au;
    ws[OFF_P + (b << 12) + n0 + tid] = pu;
  }
  const int o = tid & 63, g4 = tid >> 6;
  float bb = g_b[o];
  float acc0 = bb, acc1 = bb, acc2 = bb, acc3 = bb;
  for (int cc = 0; cc < C; ++cc) {
    float gv = gwT[cc * C + o];                 // stride-1: conflict-free
    const float* xr = &xl[cc * 16 + (g4 << 2)]; // wave broadcast
    acc0 += gv * xr[0]; acc1 += gv * xr[1]; acc2 += gv * xr[2]; acc3 += gv * xr[3];
  }
  float* gx = ws + OFF_GX + (size_t)((b << 12) + n0 + (g4 << 2)) * C + o;
  gx[0] = acc0; gx[64] = acc1; gx[128] = acc2; gx[192] = acc3;
  // ---- C_k zero scan (67 MB, grid-strided, HBM-bound) ----
  const float4* c4 = (const float4*)Ck;
  bool nz = false;
  int idx = (blockIdx.x << 8) + tid;           // 262144 threads, 16 f4 each
  for (int t = 0; t < 16; ++t) {
    float4 v = c4[idx];
    nz |= (v.x != 0.f) | (v.y != 0.f) | (v.z != 0.f) | (v.w != 0.f);
    idx += 262144;
  }
  if (__any(nz) && (tid & 63) == 0)
    atomicExch((int*)ws + OFF_FLAG, MAGIC);
}

//========== hierarchical grid barrier: 16 groups x 16 blocks + root ==========
__device__ __forceinline__ void gridbar(int* bar, int slot) {
  __syncthreads();
  if (threadIdx.x == 0) {
    __threadfence();   // release: make this block's writes device-visible
    int* base = bar + slot * 544;
    int* g    = base + (blockIdx.x & 15) * 32;   // group lines 128 B apart
    int* root = base + 512;
    if (__hip_atomic_fetch_add(g, 1, __ATOMIC_RELAXED,
                               __HIP_MEMORY_SCOPE_AGENT) == 15)
      __hip_atomic_fetch_add(root, 1, __ATOMIC_RELAXED,
                             __HIP_MEMORY_SCOPE_AGENT);
    while (__hip_atomic_load(root, __ATOMIC_RELAXED,
                             __HIP_MEMORY_SCOPE_AGENT) < 16) {
      __builtin_amdgcn_s_sleep(1);
    }
    __threadfence();   // acquire: discard stale cached lines
  }
  __syncthreads();
}

//========== fused: rank+scatter | bar | chunk sums | bar | output ============
__global__ __launch_bounds__(1024) void fused(const float* __restrict__ Ck,
                                              float* __restrict__ ws,
                                              float* __restrict__ y) {
  __shared__ float smem[12416];   // 48.5 KB, aliased per phase
  const int tid = threadIdx.x;
  const int bid = blockIdx.x;     // 256 blocks (1/CU, coop launch)
  int* bar = (int*)ws + OFF_BAR;
  const int b  = bid >> 6;        // batch
  const int rg = bid & 63;        // per-batch block index

  //---- Phase R: rank-by-counting + scatter (64 rows per block) ----
  {
    float* lp = smem;                        // 4096 floats
    int* partials = (int*)(smem + 4096);     // 64 x 17 (pad)
    const float* p = ws + OFF_P + b * N;
    ((float4*)lp)[tid] = ((const float4*)p)[tid];
    const int row = tid & 63, chunk = tid >> 6;   // 16 chunks x 256 cols
    const int i = (rg << 6) + row;
    __syncthreads();
    const float my = lp[i];
    const int c0 = chunk << 8;
    const float4* lp4 = (const float4*)(lp + c0);
    int r0 = 0, r1 = 0, r2 = 0, r3 = 0;
    for (int j = 0; j < 64; ++j) {
      float4 v = lp4[j];                     // wave broadcast read
      int k = c0 + (j << 2);
      r0 += (v.x < my) || (v.x == my && (k + 0) < i);
      r1 += (v.y < my) || (v.y == my && (k + 1) < i);
      r2 += (v.z < my) || (v.z == my && (k + 2) < i);
      r3 += (v.w < my) || (v.w == my && (k + 3) < i);
    }
    partials[row * 17 + chunk] = (r0 + r1) + (r2 + r3);
    __syncthreads();
    if (tid < 64) {
      int rank = 0;
#pragma unroll
      for (int c2 = 0; c2 < 16; ++c2) rank += partials[tid * 17 + c2];
      const int ii = (rg << 6) + tid;
      ws[OFF_Q + (b << 12) + rank] = lp[ii];
      ((int*)ws)[OFF_PERM + (b << 12) + rank] = ii;
    }
  }
  gridbar(bar, 0);

  //---- Phase S: chunk channel sums S1/S2 + scalar sums (chunk c = rg) ----
  {
    const int c = rg;
    const int o = tid & 63, kk = tid >> 6;   // 16 k-groups of 4
    const float* q = ws + OFF_Q + b * N;
    const int* perm = (const int*)ws + OFF_PERM + b * N;
    const float* gx = ws + OFF_GX + ((size_t)b << 18);
    float p1 = 0.f, p2 = 0.f, se1 = 0.f, se2 = 0.f;
    const int k0 = (c << 6) + (kk << 2);
    for (int r = 0; r < 4; ++r) {
      int k = k0 + r;
      float qv = q[k];                       // wave-broadcast global
      float e1v = expf(qv), e2v = expf(0.2f * qv);
      float g = gx[((size_t)perm[k] << 6) + o];   // coalesced row gather
      p1 += e1v * g; p2 += e2v * g;
      se1 += e1v; se2 += e2v;
    }
    float* sA = smem; float* sB = smem + 1024;
    float* ss1 = smem + 2048; float* ss2 = smem + 2064;
    sA[(kk << 6) + o] = p2;
    sB[(kk << 6) + o] = p1;
    if (o == 0) { ss1[kk] = se1; ss2[kk] = se2; }
    __syncthreads();
    if (tid < 64) {
      float t2 = 0.f, t1 = 0.f;
#pragma unroll
      for (int g2 = 0; g2 < 16; ++g2) { t2 += sA[(g2 << 6) + o]; t1 += sB[(g2 << 6) + o]; }
      ws[OFF_S2 + (size_t)(((b << 6) + c) << 6) + o] = t2;
      ws[OFF_S1 + (size_t)(((b << 6) + c) << 6) + o] = t1;
    } else if (tid == 64) {
      float t1 = 0.f, t2 = 0.f;
#pragma unroll
      for (int g2 = 0; g2 < 16; ++g2) { t1 += ss1[g2]; t2 += ss2[g2]; }
      ws[OFF_SC1 + (b << 6) + c] = t1;
      ws[OFF_SC2 + (b << 6) + c] = t2;
    }
  }
  gridbar(bar, 1);

  //---- Phase O: chunk offsets in LDS + within-chunk remainder + output ----
  {
    float* lq    = smem;           // 4096 sorted q
    float* offP  = smem + 4096;    // [c][o] prefix of S2 (chunks < c)
    float* offS  = smem + 8192;    // [c][o] suffix of S1 (chunks > c)
    float* offPS = smem + 12288;   // 64 scalar prefix
    float* offSS = smem + 12352;   // 64 scalar suffix
    ((float4*)lq)[tid] = ((const float4*)(ws + OFF_Q + b * N))[tid];
    if (tid < 64) {
      const float* S2g = ws + OFF_S2 + ((size_t)b << 12);
      float run = 0.f;
      for (int c2 = 0; c2 < 64; ++c2) { offP[(c2 << 6) + tid] = run; run += S2g[(c2 << 6) + tid]; }
    } else if (tid < 128) {
      const int o = tid - 64;
      const float* S1g = ws + OFF_S1 + ((size_t)b << 12);
      float run = 0.f;
      for (int c2 = 63; c2 >= 0; --c2) { offS[(c2 << 6) + o] = run; run += S1g[(c2 << 6) + o]; }
    } else if (tid == 128) {
      const float* sc2 = ws + OFF_SC2 + (b << 6);
      float run = 0.f;
      for (int c2 = 0; c2 < 64; ++c2) { offPS[c2] = run; run += sc2[c2]; }
    } else if (tid == 129) {
      const float* sc1 = ws + OFF_SC1 + (b << 6);
      float run = 0.f;
      for (int c2 = 63; c2 >= 0; --c2) { offSS[c2] = run; run += sc1[c2]; }
    }
    __syncthreads();
    const int io = tid & 63, og = tid >> 6;   // 16 threads/row, 4 o's each
    const int i = (rg << 6) + io;
    const float ai = ws[OFF_A + (b << 12) + i];
    const float thr = -ai;
    int lo = 0, hi = N;
    while (lo < hi) { int m = (lo + hi) >> 1; if (lq[m] <= thr) lo = m + 1; else hi = m; }
    const int k = lo;                   // first index with q > -a_i
    const int ce = min(k >> 6, 63);     // clamp handles k==N exactly
    const int j0 = ce << 6;
    const float e1 = expf(ai), e2 = expf(0.2f * ai);
    const int* perm = (const int*)ws + OFF_PERM + b * N;
    const float* gxb = ws + OFF_GX + ((size_t)b << 18) + (og << 2);
    float4 acc = {0.f, 0.f, 0.f, 0.f};
    float ds = 0.f;
    for (int j = j0; j < j0 + 64; ++j) {
      float t = ai + lq[j];
      float targ = (j < k) ? 0.2f * t : t;   // lrelu branch select
      float w = expf(targ);                  // ONE exp per j
      int pj = perm[j];                      // L1-hot scalar gather
      const float4 g4 = *(const float4*)(gxb + ((size_t)pj << 6));
      acc.x += w * g4.x; acc.y += w * g4.y; acc.z += w * g4.z; acc.w += w * g4.w;
      ds += w;
    }
    float den = e1 * offSS[ce] + e2 * offPS[ce] + ds;
    float inv = 1.0f / den;
    float4 op4 = *(float4*)(offP + (ce << 6) + (og << 2));
    float4 os4 = *(float4*)(offS + (ce << 6) + (og << 2));
    float* yb = y + ((size_t)((b << 6) + (og << 2))) * N + i;
    yb[0]             = (e1 * os4.x + e2 * op4.x + acc.x) * inv;
    yb[(size_t)N]     = (e1 * os4.y + e2 * op4.y + acc.y) * inv;
    yb[(size_t)2 * N] = (e1 * os4.z + e2 * op4.z + acc.z) * inv;
    yb[(size_t)3 * N] = (e1 * os4.w + e2 * op4.w + acc.w) * inv;
  }

  //---- Phase F: gated fallback y += C_k @ g_x (never taken here) ----
  // This block owns the same y rows it just wrote: __syncthreads suffices.
  if (((const volatile int*)ws)[OFF_FLAG] == MAGIC) {
    __syncthreads();
    const int o = tid & 63, jj = tid >> 6;
    const float* gx = ws + OFF_GX + ((size_t)b << 18);
    float (*red)[64] = (float(*)[64])smem;
    for (int ii = 0; ii < 64; ++ii) {
      int irow = (rg << 6) + ii;
      float acc2 = 0.f;
      for (int j = jj; j < N; j += 16)
        acc2 += Ck[(size_t)irow * N + j] * gx[((size_t)j << 6) + o];
      red[jj][o] = acc2;
      __syncthreads();
      if (jj == 0) {
        float s = 0.f;
#pragma unroll
        for (int g2 = 0; g2 < 16; ++g2) s += red[g2][o];
        y[((size_t)((b << 6) + o)) * N + irow] += s;
      }
      __syncthreads();
    }
  }
}

extern "C" void kernel_launch(void* const* d_in, const int* in_sizes, int n_in,
                              void* d_out, int out_size, void* d_ws, size_t ws_size,
                              hipStream_t stream) {
  (void)in_sizes; (void)n_in; (void)out_size; (void)ws_size;
  const float* x       = (const float*)d_in[0];
  const float* g_w     = (const float*)d_in[1];
  const float* g_b     = (const float*)d_in[2];
  const float* theta_w = (const float*)d_in[3];
  const float* theta_b = (const float*)d_in[4];
  const float* phi_w   = (const float*)d_in[5];
  const float* phi_b   = (const float*)d_in[6];
  const float* cp_w    = (const float*)d_in[7];
  const float* Ck      = (const float*)d_in[8];
  float* ws = (float*)d_ws;
  float* y  = (float*)d_out;

  hipLaunchKernelGGL(k1_gx, dim3(1024), dim3(256), 0, stream,
                     x, g_w, g_b, theta_w, theta_b, phi_w, phi_b, cp_w, Ck, ws);
  void* args[] = {(void*)&Ck, (void*)&ws, (void*)&y};
  hipLaunchCooperativeKernel((const void*)fused, dim3(NBLK), dim3(1024), args,
                             0, stream);
}

// Round 10
// 186.266 us; speedup vs baseline: 1.2210x; 1.2210x over previous
//
#include <hip/hip_runtime.h>

// GlobalGraphConv: B=4, C=64, N=4096, IC=32
// f[i,j] = a_i + p_j (outer sum); lrelu piecewise-linear =>
// exp(lrelu(a_i+p_j)) factorizes per branch; sort p, softmax row = chunk
// lookup (prefix/suffix chunk sums of weighted g_x) + 64-wide remainder.
// R10: coop launches carry ~45us harness overhead (R6/R7/R9 accounting) and
// R9's remainder mapping was lane-divergent. Plain 4-dispatch pipeline:
// k1 (gx+a/p+Ck scan), k2 (rank+scatter), k3 (chunk sums), k4 (output,
// ONE WAVE PER ROW: uniform remainder loop, coalesced gx reads, transposed
// coalesced y write via LDS). PreG/SufG materialization eliminated.

#define B  4
#define C  64
#define N  4096
#define IC 32
#define MAGIC 0x13572468

// workspace float offsets
#define OFF_FLAG   248                  // int: C_k nonzero marker
#define OFF_A      256
#define OFF_P      (OFF_A + B*N)
#define OFF_Q      (OFF_P + B*N)
#define OFF_PERM   (OFF_Q + B*N)        // ints
#define OFF_S1     (OFF_PERM + B*N)     // B*64*64 chunk channel sums (e^q)
#define OFF_S2     (OFF_S1 + B*64*64)   // e^{0.2q}
#define OFF_SC1    (OFF_S2 + B*64*64)   // B*64 chunk scalar sums (e^q)
#define OFF_SC2    (OFF_SC1 + B*64)     // e^{0.2q}
#define OFF_GX     (OFF_SC2 + B*64)     // B*N*64, layout [b][n][o]

//========== K1: gx = g_w@x + g_b; a,p; + grid-strided C_k zero scan ==========
__global__ __launch_bounds__(256) void k1_gx(
    const float* __restrict__ x, const float* __restrict__ g_w,
    const float* __restrict__ g_b, const float* __restrict__ theta_w,
    const float* __restrict__ theta_b, const float* __restrict__ phi_w,
    const float* __restrict__ phi_b, const float* __restrict__ cp_w,
    const float* __restrict__ Ck, float* __restrict__ ws) {
  __shared__ float gwT[C * C];   // [cc][o]
  __shared__ float xl[C * 16];   // [cc][nn]
  __shared__ float lu[C], lv[C], cst[2];
  const int tid = threadIdx.x;
  const int b = blockIdx.x >> 8;           // 256 blocks per batch
  const int n0 = (blockIdx.x & 255) << 4;  // 16 nodes per block
  for (int idx = tid; idx < C * C; idx += 256) {
    int o = idx >> 6, cc = idx & 63;
    gwT[cc * C + o] = g_w[idx];
  }
  for (int idx = tid; idx < C * 16; idx += 256) {
    int cc = idx >> 4, nn = idx & 15;
    xl[idx] = x[(size_t)((b << 6) + cc) * N + n0 + nn];
  }
  if (tid < 64) {
    float u = 0.f;
    for (int k = 0; k < IC; ++k) u += cp_w[k] * theta_w[k * C + tid];
    lu[tid] = u;
  } else if (tid < 128) {
    int c = tid - 64;
    float v = 0.f;
    for (int k = 0; k < IC; ++k) v += cp_w[IC + k] * phi_w[k * C + c];
    lv[c] = v;
  } else if (tid == 128) {
    float ca = 0.f, cp2 = 0.f;
    for (int k = 0; k < IC; ++k) { ca += cp_w[k] * theta_b[k]; cp2 += cp_w[IC + k] * phi_b[k]; }
    cst[0] = ca; cst[1] = cp2;
  }
  __syncthreads();
  if (tid < 16) {   // a,p: one thread per node
    float au = cst[0], pu = cst[1];
    for (int cc = 0; cc < C; ++cc) {
      float xv = xl[cc * 16 + tid];
      au += lu[cc] * xv;
      pu += lv[cc] * xv;
    }
    ws[OFF_A + (b << 12) + n0 + tid] = au;
    ws[OFF_P + (b << 12) + n0 + tid] = pu;
  }
  const int o = tid & 63, g4 = tid >> 6;
  float bb = g_b[o];
  float acc0 = bb, acc1 = bb, acc2 = bb, acc3 = bb;
  for (int cc = 0; cc < C; ++cc) {
    float gv = gwT[cc * C + o];                 // stride-1: conflict-free
    const float* xr = &xl[cc * 16 + (g4 << 2)]; // wave broadcast
    acc0 += gv * xr[0]; acc1 += gv * xr[1]; acc2 += gv * xr[2]; acc3 += gv * xr[3];
  }
  float* gx = ws + OFF_GX + (size_t)((b << 12) + n0 + (g4 << 2)) * C + o;
  gx[0] = acc0; gx[64] = acc1; gx[128] = acc2; gx[192] = acc3;
  // ---- C_k zero scan (67 MB, grid-strided, HBM-bound) ----
  const float4* c4 = (const float4*)Ck;
  bool nz = false;
  int idx = (blockIdx.x << 8) + tid;           // 262144 threads, 16 f4 each
  for (int t = 0; t < 16; ++t) {
    float4 v = c4[idx];
    nz |= (v.x != 0.f) | (v.y != 0.f) | (v.z != 0.f) | (v.w != 0.f);
    idx += 262144;
  }
  if (__any(nz) && (tid & 63) == 0)
    atomicExch((int*)ws + OFF_FLAG, MAGIC);
}

//========== K2: rank-by-counting + scatter (fused; R8-proven) ================
__global__ __launch_bounds__(1024) void k2_rank(float* __restrict__ ws) {
  __shared__ float lp[N];            // 16 KB: full batch p
  __shared__ int partials[32][33];   // +1 pad
  const int tid = threadIdx.x;
  const int b = blockIdx.x >> 7;
  const int rg = blockIdx.x & 127;
  const float* p = ws + OFF_P + b * N;
  ((float4*)lp)[tid] = ((const float4*)p)[tid];
  const int row = tid & 31, chunk = tid >> 5;
  const int i = (rg << 5) + row;     // batch-local row index
  __syncthreads();
  const float my = lp[i];
  const int c0 = chunk << 7;         // 128 cols per chunk
  const float4* lp4 = (const float4*)(lp + c0);
  int r0 = 0, r1 = 0, r2 = 0, r3 = 0;
  for (int j = 0; j < 32; ++j) {
    float4 v = lp4[j];               // 2 addrs/wave: free 2-way broadcast
    int k = c0 + (j << 2);
    r0 += (v.x < my) || (v.x == my && (k + 0) < i);
    r1 += (v.y < my) || (v.y == my && (k + 1) < i);
    r2 += (v.z < my) || (v.z == my && (k + 2) < i);
    r3 += (v.w < my) || (v.w == my && (k + 3) < i);
  }
  partials[row][chunk] = (r0 + r1) + (r2 + r3);
  __syncthreads();
  if (tid < 32) {                    // one thread per row: finalize + scatter
    int rank = 0;
#pragma unroll
    for (int c = 0; c < 32; ++c) rank += partials[tid][c];
    const int ii = (rg << 5) + tid;
    ws[OFF_Q + (b << 12) + rank] = lp[ii];
    ((int*)ws)[OFF_PERM + (b << 12) + rank] = ii;
  }
}

//========== K3: chunk channel sums S1/S2 + scalar sums (R9-proven) ===========
__global__ __launch_bounds__(1024) void k3_sums(float* __restrict__ ws) {
  __shared__ float sA[1024], sB[1024], ss1[16], ss2[16];
  const int tid = threadIdx.x;
  const int b = blockIdx.x >> 6, c = blockIdx.x & 63;
  const int o = tid & 63, kk = tid >> 6;   // 16 k-groups of 4
  const float* q = ws + OFF_Q + b * N;
  const int* perm = (const int*)ws + OFF_PERM + b * N;
  const float* gx = ws + OFF_GX + ((size_t)b << 18);
  float p1 = 0.f, p2 = 0.f, se1 = 0.f, se2 = 0.f;
  const int k0 = (c << 6) + (kk << 2);
  for (int r = 0; r < 4; ++r) {
    int k = k0 + r;
    float qv = q[k];                       // wave-broadcast global
    float e1v = expf(qv), e2v = expf(0.2f * qv);
    float g = gx[((size_t)perm[k] << 6) + o];   // coalesced row gather
    p1 += e1v * g; p2 += e2v * g;
    se1 += e1v; se2 += e2v;
  }
  sA[(kk << 6) + o] = p2;
  sB[(kk << 6) + o] = p1;
  if (o == 0) { ss1[kk] = se1; ss2[kk] = se2; }
  __syncthreads();
  if (tid < 64) {
    float t2 = 0.f, t1 = 0.f;
#pragma unroll
    for (int g2 = 0; g2 < 16; ++g2) { t2 += sA[(g2 << 6) + o]; t1 += sB[(g2 << 6) + o]; }
    ws[OFF_S2 + (size_t)(((b << 6) + c) << 6) + o] = t2;
    ws[OFF_S1 + (size_t)(((b << 6) + c) << 6) + o] = t1;
  } else if (tid == 64) {
    float t1 = 0.f, t2 = 0.f;
#pragma unroll
    for (int g2 = 0; g2 < 16; ++g2) { t1 += ss1[g2]; t2 += ss2[g2]; }
    ws[OFF_SC1 + (b << 6) + c] = t1;
    ws[OFF_SC2 + (b << 6) + c] = t2;
  }
}

//========== K4: output — one wave per row; chunk offsets + remainder =========
__global__ __launch_bounds__(1024) void k4_out(const float* __restrict__ Ck,
                                               float* __restrict__ ws,
                                               float* __restrict__ y) {
  __shared__ float offP[4096];   // [c][o] prefix of S2 (chunks < c)
  __shared__ float offS[4096];   // [c][o] suffix of S1 (chunks > c)
  __shared__ float yblk[4096];   // [row][o]
  __shared__ float cmax[64], offPS[64], offSS[64];
  const int tid = threadIdx.x;
  const int b = blockIdx.x >> 6, rg = blockIdx.x & 63;   // 64 rows per block
  const float* q = ws + OFF_Q + b * N;
  const int* perm = (const int*)ws + OFF_PERM + b * N;
  if (tid < 64) {
    const float* S2g = ws + OFF_S2 + ((size_t)b << 12);
    float run = 0.f;
    for (int c2 = 0; c2 < 64; ++c2) { offP[(c2 << 6) + tid] = run; run += S2g[(c2 << 6) + tid]; }
  } else if (tid < 128) {
    const int o = tid - 64;
    const float* S1g = ws + OFF_S1 + ((size_t)b << 12);
    float run = 0.f;
    for (int c2 = 63; c2 >= 0; --c2) { offS[(c2 << 6) + o] = run; run += S1g[(c2 << 6) + o]; }
  } else if (tid == 128) {
    const float* sc2 = ws + OFF_SC2 + (b << 6);
    float run = 0.f;
    for (int c2 = 0; c2 < 64; ++c2) { offPS[c2] = run; run += sc2[c2]; }
  } else if (tid == 129) {
    const float* sc1 = ws + OFF_SC1 + (b << 6);
    float run = 0.f;
    for (int c2 = 63; c2 >= 0; --c2) { offSS[c2] = run; run += sc1[c2]; }
  } else if (tid >= 192 && tid < 256) {
    cmax[tid - 192] = q[((tid - 192) << 6) + 63];   // per-chunk max (sorted)
  }
  __syncthreads();
  const int wave = tid >> 6, lane = tid & 63;   // lane = output channel o
  const float* gxb = ws + OFF_GX + ((size_t)b << 18);
  for (int rr = 0; rr < 4; ++rr) {
    const int row = (wave << 2) + rr;           // 0..63
    const int i = (rg << 6) + row;
    const float ai = ws[OFF_A + (b << 12) + i]; // wave-uniform
    const float thr = -ai;
    int lo = 0, hi = 64;                        // find first chunk w/ max > thr
    while (lo < hi) { int m = (lo + hi) >> 1; if (cmax[m] <= thr) lo = m + 1; else hi = m; }
    const int ce = min(lo, 63);                 // clamp: k==N case
    const int j0 = ce << 6;
    const float e1 = expf(ai), e2 = expf(0.2f * ai);
    float acc = 0.f, dsum = 0.f;
    for (int j = j0; j < j0 + 64; ++j) {
      float qj = q[j];                          // wave-uniform (L2-hot)
      float t = ai + qj;
      float w = expf((qj <= thr) ? 0.2f * t : t);   // == (j<k) branch select
      int pj = perm[j];                         // wave-uniform
      acc += w * gxb[((size_t)pj << 6) + lane]; // coalesced 256 B
      dsum += w;
    }
    float den = e1 * offSS[ce] + e2 * offPS[ce] + dsum;
    yblk[(row << 6) + lane] =
        (e1 * offS[(ce << 6) + lane] + e2 * offP[(ce << 6) + lane] + acc) / den;
  }
  __syncthreads();
  {  // transposed coalesced write: y[b*C+o][rg*64 .. +63]
    const int o = tid >> 4, i4 = tid & 15;
    float4 v;
    v.x = yblk[(((i4 << 2) + 0) << 6) + o];
    v.y = yblk[(((i4 << 2) + 1) << 6) + o];
    v.z = yblk[(((i4 << 2) + 2) << 6) + o];
    v.w = yblk[(((i4 << 2) + 3) << 6) + o];
    *(float4*)(y + ((size_t)((b << 6) + o)) * N + (rg << 6) + (i4 << 2)) = v;
  }
  // ---- gated fallback y += C_k @ g_x (never taken in this harness) ----
  if (((const volatile int*)ws)[OFF_FLAG] == MAGIC) {
    __syncthreads();
    const int o = tid & 63, jj = tid >> 6;
    float (*red)[64] = (float(*)[64])yblk;
    for (int ii = 0; ii < 64; ++ii) {
      int irow = (rg << 6) + ii;
      float acc2 = 0.f;
      for (int j = jj; j < N; j += 16)
        acc2 += Ck[(size_t)irow * N + j] * gxb[((size_t)j << 6) + o];
      red[jj][o] = acc2;
      __syncthreads();
      if (jj == 0) {
        float s = 0.f;
#pragma unroll
        for (int g2 = 0; g2 < 16; ++g2) s += red[g2][o];
        y[((size_t)((b << 6) + o)) * N + irow] += s;
      }
      __syncthreads();
    }
  }
}

extern "C" void kernel_launch(void* const* d_in, const int* in_sizes, int n_in,
                              void* d_out, int out_size, void* d_ws, size_t ws_size,
                              hipStream_t stream) {
  (void)in_sizes; (void)n_in; (void)out_size; (void)ws_size;
  const float* x       = (const float*)d_in[0];
  const float* g_w     = (const float*)d_in[1];
  const float* g_b     = (const float*)d_in[2];
  const float* theta_w = (const float*)d_in[3];
  const float* theta_b = (const float*)d_in[4];
  const float* phi_w   = (const float*)d_in[5];
  const float* phi_b   = (const float*)d_in[6];
  const float* cp_w    = (const float*)d_in[7];
  const float* Ck      = (const float*)d_in[8];
  float* ws = (float*)d_ws;
  float* y  = (float*)d_out;

  hipLaunchKernelGGL(k1_gx, dim3(1024), dim3(256), 0, stream,
                     x, g_w, g_b, theta_w, theta_b, phi_w, phi_b, cp_w, Ck, ws);
  hipLaunchKernelGGL(k2_rank, dim3(512), dim3(1024), 0, stream, ws);
  hipLaunchKernelGGL(k3_sums, dim3(B * 64), dim3(1024), 0, stream, ws);
  hipLaunchKernelGGL(k4_out, dim3(B * 64), dim3(1024), 0, stream, Ck, ws, y);
}

// Round 11
// 170.219 us; speedup vs baseline: 1.3361x; 1.0943x over previous
//
#include <hip/hip_runtime.h>

// GlobalGraphConv: B=4, C=64, N=4096, IC=32
// f[i,j] = a_i + p_j (outer sum); lrelu piecewise-linear =>
// exp(lrelu(a_i+p_j)) factorizes per branch; sort p, softmax row = chunk
// offsets + within-chunk remainder over PRE-SCALED sorted gx rows.
// R11: R10's k4 was VALU-bound (74% busy, 61us) on redundant per-lane exp +
// perm gathers. k3 now materializes gs1[j]=e^{q_j} gx[perm_j], gs2[j]=
// e^{0.2 q_j} gx[perm_j] (one exp per j TOTAL) + per-element PreS/SufS
// scans (R8-proven). k4 inner loop = pure sequential load+add, split at k
// (wave-uniform bounds). yblk stride-65 kills the transpose bank conflict.

#define B  4
#define C  64
#define N  4096
#define IC 32
#define NS 4104
#define MAGIC 0x13572468

// workspace float offsets
#define OFF_FLAG   248                   // int: C_k nonzero marker
#define OFF_A      256
#define OFF_P      (OFF_A + B*N)         // 16640
#define OFF_Q      (OFF_P + B*N)         // 33024
#define OFF_PERM   (OFF_Q + B*N)         // 49408 (ints)
#define OFF_PRES   (OFF_PERM + B*N)      // 65792  B*NS excl prefix e^{0.2q}
#define OFF_SUFS   (OFF_PRES + B*NS)     // 82208  B*NS incl suffix e^{q}
#define OFF_S1     (OFF_SUFS + B*NS)     // 98624  B*64*64 chunk ch-sums (e^q g)
#define OFF_S2     (OFF_S1 + B*64*64)    // 115008 (e^{0.2q} g)
#define OFF_GX     (OFF_S2 + B*64*64)    // 131392 B*N*64 [b][n][o]
#define OFF_GS1    (OFF_GX + B*N*64)     // sorted rows scaled by e^{q}
#define OFF_GS2    (OFF_GS1 + B*N*64)    // sorted rows scaled by e^{0.2q}

//========== K1: gx = g_w@x + g_b; a,p; + grid-strided C_k zero scan ==========
__global__ __launch_bounds__(256) void k1_gx(
    const float* __restrict__ x, const float* __restrict__ g_w,
    const float* __restrict__ g_b, const float* __restrict__ theta_w,
    const float* __restrict__ theta_b, const float* __restrict__ phi_w,
    const float* __restrict__ phi_b, const float* __restrict__ cp_w,
    const float* __restrict__ Ck, float* __restrict__ ws) {
  __shared__ float gwT[C * C];   // [cc][o]
  __shared__ float xl[C * 16];   // [cc][nn]
  __shared__ float lu[C], lv[C], cst[2];
  const int tid = threadIdx.x;
  const int b = blockIdx.x >> 8;           // 256 blocks per batch
  const int n0 = (blockIdx.x & 255) << 4;  // 16 nodes per block
  for (int idx = tid; idx < C * C; idx += 256) {
    int o = idx >> 6, cc = idx & 63;
    gwT[cc * C + o] = g_w[idx];
  }
  for (int idx = tid; idx < C * 16; idx += 256) {
    int cc = idx >> 4, nn = idx & 15;
    xl[idx] = x[(size_t)((b << 6) + cc) * N + n0 + nn];
  }
  if (tid < 64) {
    float u = 0.f;
    for (int k = 0; k < IC; ++k) u += cp_w[k] * theta_w[k * C + tid];
    lu[tid] = u;
  } else if (tid < 128) {
    int c = tid - 64;
    float v = 0.f;
    for (int k = 0; k < IC; ++k) v += cp_w[IC + k] * phi_w[k * C + c];
    lv[c] = v;
  } else if (tid == 128) {
    float ca = 0.f, cp2 = 0.f;
    for (int k = 0; k < IC; ++k) { ca += cp_w[k] * theta_b[k]; cp2 += cp_w[IC + k] * phi_b[k]; }
    cst[0] = ca; cst[1] = cp2;
  }
  __syncthreads();
  if (tid < 16) {   // a,p: one thread per node
    float au = cst[0], pu = cst[1];
    for (int cc = 0; cc < C; ++cc) {
      float xv = xl[cc * 16 + tid];
      au += lu[cc] * xv;
      pu += lv[cc] * xv;
    }
    ws[OFF_A + (b << 12) + n0 + tid] = au;
    ws[OFF_P + (b << 12) + n0 + tid] = pu;
  }
  const int o = tid & 63, g4 = tid >> 6;
  float bb = g_b[o];
  float acc0 = bb, acc1 = bb, acc2 = bb, acc3 = bb;
  for (int cc = 0; cc < C; ++cc) {
    float gv = gwT[cc * C + o];                 // stride-1: conflict-free
    const float* xr = &xl[cc * 16 + (g4 << 2)]; // wave broadcast
    acc0 += gv * xr[0]; acc1 += gv * xr[1]; acc2 += gv * xr[2]; acc3 += gv * xr[3];
  }
  float* gx = ws + OFF_GX + (size_t)((b << 12) + n0 + (g4 << 2)) * C + o;
  gx[0] = acc0; gx[64] = acc1; gx[128] = acc2; gx[192] = acc3;
  // ---- C_k zero scan (67 MB, grid-strided, HBM-bound) ----
  const float4* c4 = (const float4*)Ck;
  bool nz = false;
  int idx = (blockIdx.x << 8) + tid;           // 262144 threads, 16 f4 each
  for (int t = 0; t < 16; ++t) {
    float4 v = c4[idx];
    nz |= (v.x != 0.f) | (v.y != 0.f) | (v.z != 0.f) | (v.w != 0.f);
    idx += 262144;
  }
  if (__any(nz) && (tid & 63) == 0)
    atomicExch((int*)ws + OFF_FLAG, MAGIC);
}

//========== K2: rank-by-counting + scatter (fused; R8-proven) ================
__global__ __launch_bounds__(1024) void k2_rank(float* __restrict__ ws) {
  __shared__ float lp[N];            // 16 KB: full batch p
  __shared__ int partials[32][33];   // +1 pad
  const int tid = threadIdx.x;
  const int b = blockIdx.x >> 7;
  const int rg = blockIdx.x & 127;
  const float* p = ws + OFF_P + b * N;
  ((float4*)lp)[tid] = ((const float4*)p)[tid];
  const int row = tid & 31, chunk = tid >> 5;
  const int i = (rg << 5) + row;     // batch-local row index
  __syncthreads();
  const float my = lp[i];
  const int c0 = chunk << 7;         // 128 cols per chunk
  const float4* lp4 = (const float4*)(lp + c0);
  int r0 = 0, r1 = 0, r2 = 0, r3 = 0;
  for (int j = 0; j < 32; ++j) {
    float4 v = lp4[j];               // 2 addrs/wave: free 2-way broadcast
    int k = c0 + (j << 2);
    r0 += (v.x < my) || (v.x == my && (k + 0) < i);
    r1 += (v.y < my) || (v.y == my && (k + 1) < i);
    r2 += (v.z < my) || (v.z == my && (k + 2) < i);
    r3 += (v.w < my) || (v.w == my && (k + 3) < i);
  }
  partials[row][chunk] = (r0 + r1) + (r2 + r3);
  __syncthreads();
  if (tid < 32) {                    // one thread per row: finalize + scatter
    int rank = 0;
#pragma unroll
    for (int c = 0; c < 32; ++c) rank += partials[tid][c];
    const int ii = (rg << 5) + tid;
    ws[OFF_Q + (b << 12) + rank] = lp[ii];
    ((int*)ws)[OFF_PERM + (b << 12) + rank] = ii;
  }
}

//========== K3: chunk sums + pre-scaled gs1/gs2; blocks 256.. PreS/SufS ======
__global__ __launch_bounds__(1024) void k3_sums(float* __restrict__ ws) {
  __shared__ float sA[1024], sB[1024];
  const int tid = threadIdx.x;
  const int bid = blockIdx.x;
  if (bid < B * 64) {
    // ---- chunk channel sums + gs materialization ----
    const int b = bid >> 6, c = bid & 63;
    const int o = tid & 63, kk = tid >> 6;   // 16 k-groups of 4
    const float* q = ws + OFF_Q + b * N;
    const int* perm = (const int*)ws + OFF_PERM + b * N;
    const float* gx = ws + OFF_GX + ((size_t)b << 18);
    float* gs1 = ws + OFF_GS1 + ((size_t)b << 18);
    float* gs2 = ws + OFF_GS2 + ((size_t)b << 18);
    float p1 = 0.f, p2 = 0.f;
    const int k0 = (c << 6) + (kk << 2);
    for (int r = 0; r < 4; ++r) {
      int k = k0 + r;
      float qv = q[k];                       // wave-broadcast global
      float e1v = expf(qv), e2v = expf(0.2f * qv);
      float g = gx[((size_t)perm[k] << 6) + o];   // coalesced row gather
      float w1 = e1v * g, w2 = e2v * g;
      gs1[((size_t)k << 6) + o] = w1;        // coalesced 256 B
      gs2[((size_t)k << 6) + o] = w2;
      p1 += w1; p2 += w2;
    }
    sA[(kk << 6) + o] = p2;
    sB[(kk << 6) + o] = p1;
    __syncthreads();
    if (tid < 64) {
      float t2 = 0.f, t1 = 0.f;
#pragma unroll
      for (int g2 = 0; g2 < 16; ++g2) { t2 += sA[(g2 << 6) + o]; t1 += sB[(g2 << 6) + o]; }
      ws[OFF_S2 + (size_t)(((b << 6) + c) << 6) + o] = t2;
      ws[OFF_S1 + (size_t)(((b << 6) + c) << 6) + o] = t1;
    }
  } else {
    // ---- per-element PreS/SufS shuffle scans (R8-proven) ----
    const int b = bid - B * 64;
    float* wt2 = sA;        // 16
    float* wt1 = sA + 16;   // 16
    float* wo2 = sA + 32;   // 17
    float* wo1 = sA + 49;   // 17
    const float* q = ws + OFF_Q + b * N;
    const float4 qv4 = ((const float4*)q)[tid];
    float e1r[4], e2r[4];
    e2r[0] = expf(0.2f * qv4.x); e1r[0] = expf(qv4.x);
    e2r[1] = expf(0.2f * qv4.y); e1r[1] = expf(qv4.y);
    e2r[2] = expf(0.2f * qv4.z); e1r[2] = expf(qv4.z);
    e2r[3] = expf(0.2f * qv4.w); e1r[3] = expf(qv4.w);
    float s2 = e2r[0] + e2r[1] + e2r[2] + e2r[3];
    float s1 = e1r[0] + e1r[1] + e1r[2] + e1r[3];
    const int lane = tid & 63, wave = tid >> 6;   // 16 waves
    float x2 = s2, x1 = s1;
    for (int off = 1; off < 64; off <<= 1) {
      float t2 = __shfl_up(x2, off, 64);
      float t1 = __shfl_up(x1, off, 64);
      if (lane >= off) { x2 += t2; x1 += t1; }
    }
    if (lane == 63) { wt2[wave] = x2; wt1[wave] = x1; }
    __syncthreads();
    if (wave == 0 && lane < 17) {
      float a2 = 0.f, a1 = 0.f;
      for (int w = 0; w < 16; ++w) {
        if (w < lane) { a2 += wt2[w]; a1 += wt1[w]; }
      }
      wo2[lane] = a2; wo1[lane] = a1;   // wo[16] = grand totals
    }
    __syncthreads();
    const float excl2 = wo2[wave] + (x2 - s2);
    const float incl1 = wo1[wave] + x1;
    const float tot1 = wo1[16];
    float* PreS = ws + OFF_PRES + b * NS;
    float* SufS = ws + OFF_SUFS + b * NS;
    const int base = tid << 2;
    float run = excl2;
#pragma unroll
    for (int j = 0; j < 4; ++j) { PreS[base + j] = run; run += e2r[j]; }
    if (tid == 1023) PreS[N] = run;
    run = tot1 - incl1;
#pragma unroll
    for (int j = 3; j >= 0; --j) { run += e1r[j]; SufS[base + j] = run; }
    if (tid == 1023) SufS[N] = 0.f;
  }
}

//========== K4: output — wave/row; chunk offsets + load-add remainder ========
__global__ __launch_bounds__(1024) void k4_out(const float* __restrict__ Ck,
                                               float* __restrict__ ws,
                                               float* __restrict__ y) {
  __shared__ float lqy[4224];    // lq[4096] in phase 1; yblk (stride 65) after
  __shared__ float offP[4096];   // [c][o] prefix of S2 (chunks < c)
  __shared__ float offS[4096];   // [c][o] suffix of S1 (chunks > c)
  const int tid = threadIdx.x;
  const int b = blockIdx.x >> 6, rg = blockIdx.x & 63;   // 64 rows per block
  float* lq = lqy;
  ((float4*)lq)[tid] = ((const float4*)(ws + OFF_Q + b * N))[tid];
  if (tid < 64) {
    const float* S2g = ws + OFF_S2 + ((size_t)b << 12);
    float run = 0.f;
    for (int c2 = 0; c2 < 64; ++c2) { offP[(c2 << 6) + tid] = run; run += S2g[(c2 << 6) + tid]; }
  } else if (tid < 128) {
    const int o = tid - 64;
    const float* S1g = ws + OFF_S1 + ((size_t)b << 12);
    float run = 0.f;
    for (int c2 = 63; c2 >= 0; --c2) { offS[(c2 << 6) + o] = run; run += S1g[(c2 << 6) + o]; }
  }
  __syncthreads();
  const int wave = tid >> 6, lane = tid & 63;   // lane = output channel o
  // ---- phase 1: per-row search + denominator (reads lq) ----
  int r_k[4], r_ce[4];
  float r_e1[4], r_e2[4], r_inv[4];
#pragma unroll
  for (int rr = 0; rr < 4; ++rr) {
    const int row = (wave << 2) + rr;
    const int i = (rg << 6) + row;
    const float ai = ws[OFF_A + (b << 12) + i];   // wave-uniform
    const float thr = -ai;
    int lo = 0, hi = N;
    while (lo < hi) { int m = (lo + hi) >> 1; if (lq[m] <= thr) lo = m + 1; else hi = m; }
    r_k[rr] = lo;
    r_ce[rr] = min(lo >> 6, 63);
    r_e1[rr] = expf(ai);
    r_e2[rr] = expf(0.2f * ai);
    float den = r_e1[rr] * ws[OFF_SUFS + b * NS + lo] +
                r_e2[rr] * ws[OFF_PRES + b * NS + lo];
    r_inv[rr] = 1.0f / den;
  }
  __syncthreads();   // all waves done with lq; region becomes yblk
  float* yblk = lqy;  // stride 65
  // ---- phase 2: remainder = pure sequential load+add on gs1/gs2 ----
  const float* gs1 = ws + OFF_GS1 + ((size_t)b << 18) + lane;
  const float* gs2 = ws + OFF_GS2 + ((size_t)b << 18) + lane;
#pragma unroll
  for (int rr = 0; rr < 4; ++rr) {
    const int row = (wave << 2) + rr;
    const int ce = r_ce[rr], j0 = ce << 6, m = r_k[rr] - j0;   // m in [0,64]
    const float* g2p = gs2 + ((size_t)j0 << 6);
    const float* g1p = gs1 + ((size_t)j0 << 6);
    float a0 = 0.f, a1 = 0.f, a2 = 0.f, a3 = 0.f;
    float b0 = 0.f, b1 = 0.f, b2 = 0.f, b3 = 0.f;
    int j = 0;
    for (; j + 4 <= m; j += 4) {
      a0 += g2p[(size_t)(j + 0) << 6];
      a1 += g2p[(size_t)(j + 1) << 6];
      a2 += g2p[(size_t)(j + 2) << 6];
      a3 += g2p[(size_t)(j + 3) << 6];
    }
    for (; j < m; ++j) a0 += g2p[(size_t)j << 6];
    for (; j + 4 <= 64; j += 4) {
      b0 += g1p[(size_t)(j + 0) << 6];
      b1 += g1p[(size_t)(j + 1) << 6];
      b2 += g1p[(size_t)(j + 2) << 6];
      b3 += g1p[(size_t)(j + 3) << 6];
    }
    for (; j < 64; ++j) b0 += g1p[(size_t)j << 6];
    float accA = (a0 + a1) + (a2 + a3);
    float accB = (b0 + b1) + (b2 + b3);
    float num = r_e1[rr] * (offS[(ce << 6) + lane] + accB) +
                r_e2[rr] * (offP[(ce << 6) + lane] + accA);
    yblk[row * 65 + lane] = num * r_inv[rr];
  }
  __syncthreads();
  {  // transposed coalesced write: wave w -> channels [4w,4w+4), lane = i
    const int i = lane, o0 = wave << 2;
#pragma unroll
    for (int rr = 0; rr < 4; ++rr) {
      int o = o0 + rr;
      y[((size_t)((b << 6) + o)) * N + (rg << 6) + i] = yblk[i * 65 + o];
    }
  }
  // ---- gated fallback y += C_k @ g_x (never taken in this harness) ----
  if (((const volatile int*)ws)[OFF_FLAG] == MAGIC) {
    __syncthreads();
    const int o = tid & 63, jj = tid >> 6;
    const float* gxb = ws + OFF_GX + ((size_t)b << 18);
    float (*red)[64] = (float(*)[64])lqy;
    for (int ii = 0; ii < 64; ++ii) {
      int irow = (rg << 6) + ii;
      float acc2 = 0.f;
      for (int j = jj; j < N; j += 16)
        acc2 += Ck[(size_t)irow * N + j] * gxb[((size_t)j << 6) + o];
      red[jj][o] = acc2;
      __syncthreads();
      if (jj == 0) {
        float s = 0.f;
#pragma unroll
        for (int g2 = 0; g2 < 16; ++g2) s += red[g2][o];
        y[((size_t)((b << 6) + o)) * N + irow] += s;
      }
      __syncthreads();
    }
  }
}

extern "C" void kernel_launch(void* const* d_in, const int* in_sizes, int n_in,
                              void* d_out, int out_size, void* d_ws, size_t ws_size,
                              hipStream_t stream) {
  (void)in_sizes; (void)n_in; (void)out_size; (void)ws_size;
  const float* x       = (const float*)d_in[0];
  const float* g_w     = (const float*)d_in[1];
  const float* g_b     = (const float*)d_in[2];
  const float* theta_w = (const float*)d_in[3];
  const float* theta_b = (const float*)d_in[4];
  const float* phi_w   = (const float*)d_in[5];
  const float* phi_b   = (const float*)d_in[6];
  const float* cp_w    = (const float*)d_in[7];
  const float* Ck      = (const float*)d_in[8];
  float* ws = (float*)d_ws;
  float* y  = (float*)d_out;

  hipLaunchKernelGGL(k1_gx, dim3(1024), dim3(256), 0, stream,
                     x, g_w, g_b, theta_w, theta_b, phi_w, phi_b, cp_w, Ck, ws);
  hipLaunchKernelGGL(k2_rank, dim3(512), dim3(1024), 0, stream, ws);
  hipLaunchKernelGGL(k3_sums, dim3(B * 64 + B), dim3(1024), 0, stream, ws);
  hipLaunchKernelGGL(k4_out, dim3(B * 64), dim3(1024), 0, stream, Ck, ws, y);
}